// Round 8
// baseline (366.592 us; speedup 1.0000x reference)
//
#include <hip/hip_runtime.h>
#include <hip/hip_bf16.h>
#include <math.h>

#define NN 50000
#define NE 600000
#define MPAD 50048      // 1564*32
#define NT (MPAD / 32)  // 1564 tiles
#define DIM 128
#define HID 256
#define NB 49           // ceil(NN/1024)
#define HIST_BLOCKS ((NE + 255) / 256)
#define CAST_BLOCKS ((4 * DIM * HID) / 256)
#define EPS_MSG 1e-7f
#define EPS_NORM 1e-5f

typedef __attribute__((ext_vector_type(8))) short short8v;
typedef __attribute__((ext_vector_type(8))) unsigned short ushort8v;
typedef __attribute__((ext_vector_type(4))) float f32x4;

__device__ inline ushort f2bf(float f) {
    union { float f; unsigned u; } v; v.f = f;
    unsigned r = v.u + 0x7FFF + ((v.u >> 16) & 1);
    return (ushort)(r >> 16);
}
__device__ inline float bf2f(ushort u) {
    union { unsigned u; float f; } v; v.u = (unsigned)u << 16; return v.f;
}

// ---- fused setup: blocks [0,64) xstats | [64,64+HIST) hist | rest weight cast+T ----
__global__ __launch_bounds__(256) void k_setup(const float* __restrict__ x,
                                               const int* __restrict__ dst,
                                               const float* __restrict__ W1,
                                               const float* __restrict__ W2,
                                               float* __restrict__ xs,
                                               int* __restrict__ deg,
                                               ushort* __restrict__ W1t,
                                               ushort* __restrict__ W2t) {
    int b = blockIdx.x;
    if (b < 64) {
        int lane = threadIdx.x & 63;
        float s = 0.f, q = 0.f;
        for (int i = b * 256 + threadIdx.x; i < NN; i += 64 * 256) {
            float v = x[i];
            s += v; q += v * v;
        }
        #pragma unroll
        for (int off = 32; off >= 1; off >>= 1) {
            s += __shfl_xor(s, off, 64);
            q += __shfl_xor(q, off, 64);
        }
        if (lane == 0) { atomicAdd(&xs[0], s); atomicAdd(&xs[1], q); }
    } else if (b < 64 + HIST_BLOCKS) {
        int i = (b - 64) * 256 + threadIdx.x;
        if (i < NE) atomicAdd(&deg[dst[i]], 1);
    } else {
        const int chunk = DIM * HID;
        int i = (b - 64 - HIST_BLOCKS) * 256 + threadIdx.x;
        int w = i / chunk;
        int j = i - w * chunk;
        if (w < 2) {
            int r = j / HID, c = j - r * HID;
            W1t[(size_t)w * chunk + (size_t)c * DIM + r] = f2bf(W1[(size_t)w * chunk + j]);
        } else {
            int l = w - 2;
            int r = j / DIM, c = j - r * DIM;
            W2t[(size_t)l * chunk + (size_t)c * HID + r] = f2bf(W2[(size_t)l * chunk + j]);
        }
    }
}

// ------- layer-0 hn (bf16): BN params in closed form (h = x*Wn + bnb is rank-1) -------
__global__ void k_hn0(const float* __restrict__ x, const float* __restrict__ xs,
                      const float* __restrict__ Wn, const float* __restrict__ bnb,
                      const float* __restrict__ gamma, const float* __restrict__ beta,
                      ushort* __restrict__ hn, int total4) {
    int i = blockIdx.x * blockDim.x + threadIdx.x;
    if (i >= total4) return;
    int d4 = (i & 31) * 4;
    int n = i >> 5;
    float mx = xs[0] * (1.f / NN);
    float vx = xs[1] * (1.f / NN) - mx * mx;
    float xv = x[n];
    float4 w = *(const float4*)(Wn + d4);
    float4 b = *(const float4*)(bnb + d4);
    float4 g = *(const float4*)(gamma + d4);
    float4 bt = *(const float4*)(beta + d4);
    ushort4 o;
    {
        float mu = fmaf(mx, w.x, b.x), sc = rsqrtf(vx * w.x * w.x + EPS_NORM) * g.x;
        o.x = f2bf(fmaxf(fmaf(fmaf(xv, w.x, b.x) - mu, sc, bt.x), 0.f));
    }
    {
        float mu = fmaf(mx, w.y, b.y), sc = rsqrtf(vx * w.y * w.y + EPS_NORM) * g.y;
        o.y = f2bf(fmaxf(fmaf(fmaf(xv, w.y, b.y) - mu, sc, bt.y), 0.f));
    }
    {
        float mu = fmaf(mx, w.z, b.z), sc = rsqrtf(vx * w.z * w.z + EPS_NORM) * g.z;
        o.z = f2bf(fmaxf(fmaf(fmaf(xv, w.z, b.z) - mu, sc, bt.z), 0.f));
    }
    {
        float mu = fmaf(mx, w.w, b.w), sc = rsqrtf(vx * w.w * w.w + EPS_NORM) * g.w;
        o.w = f2bf(fmaxf(fmaf(fmaf(xv, w.w, b.w) - mu, sc, bt.w), 0.f));
    }
    *(ushort4*)(hn + (size_t)n * DIM + d4) = o;
}

// ---------------- CSR build (multi-block scan) ----------------
__global__ __launch_bounds__(256) void k_scanA(const int* __restrict__ deg,
                                               int* __restrict__ partials, int n) {
    __shared__ int ws[4];
    int b = blockIdx.x;
    int t = threadIdx.x;
    int s = 0;
    #pragma unroll
    for (int i = 0; i < 4; ++i) {
        int idx = b * 1024 + t + i * 256;
        s += (idx < n) ? deg[idx] : 0;
    }
    #pragma unroll
    for (int off = 32; off >= 1; off >>= 1) s += __shfl_xor(s, off, 64);
    if ((t & 63) == 0) ws[t >> 6] = s;
    __syncthreads();
    if (t == 0) partials[b] = ws[0] + ws[1] + ws[2] + ws[3];
}

__global__ __launch_bounds__(64) void k_scanB(const int* __restrict__ partials,
                                              int* __restrict__ base,
                                              int* __restrict__ row_off) {
    int t = threadIdx.x;
    int v = (t < NB) ? partials[t] : 0;
    int x = v;
    #pragma unroll
    for (int off = 1; off < 64; off <<= 1) {
        int y = __shfl_up(x, off, 64);
        if (t >= off) x += y;
    }
    if (t < NB) base[t] = x - v;
    if (t == 0) row_off[NN] = NE;
}

__global__ __launch_bounds__(1024) void k_scanC(const int* __restrict__ deg,
                                                const int* __restrict__ base,
                                                int* __restrict__ row_off,
                                                int* __restrict__ cursor, int n) {
    __shared__ int wsum[16];
    int i = blockIdx.x * 1024 + threadIdx.x;
    int lane = threadIdx.x & 63;
    int wid = threadIdx.x >> 6;
    int v = (i < n) ? deg[i] : 0;
    int x = v;
    #pragma unroll
    for (int off = 1; off < 64; off <<= 1) {
        int y = __shfl_up(x, off, 64);
        if (lane >= off) x += y;
    }
    if (lane == 63) wsum[wid] = x;
    __syncthreads();
    if (wid == 0 && lane < 16) {
        int w = wsum[lane];
        #pragma unroll
        for (int off = 1; off < 16; off <<= 1) {
            int y = __shfl_up(w, off, 64);
            if (lane >= off) w += y;
        }
        wsum[lane] = w;
    }
    __syncthreads();
    int prev = (wid == 0) ? 0 : wsum[wid - 1];
    int excl = base[blockIdx.x] + prev + (x - v);
    if (i < n) { row_off[i] = excl; cursor[i] = excl; }
}

// scatter edge record {src, eid, ea_bits, 0} to CSR slot (one 16B store)
__global__ void k_scatter(const int* __restrict__ src, const int* __restrict__ dst,
                          const float* __restrict__ eattr, int* __restrict__ cursor,
                          int4* __restrict__ erec, int E) {
    int i = blockIdx.x * blockDim.x + threadIdx.x;
    if (i >= E) return;
    int d = dst[i];
    int pos = atomicAdd(&cursor[d], 1);
    erec[pos] = make_int4(src[i], i, __float_as_int(eattr[i]), 0);
}

// ------- BN apply + ReLU -> bf16 hn (finalize fused per-thread from raw stats) -------
__global__ void k_bn_relu(const float* __restrict__ h, const float* __restrict__ stats,
                          const float* __restrict__ gamma, const float* __restrict__ beta,
                          ushort* __restrict__ hn, int total4) {
    int i = blockIdx.x * blockDim.x + threadIdx.x;
    if (i >= total4) return;
    int d4 = (i & 31) * 4;
    int n = i >> 5;
    float4 v = *(const float4*)(h + (size_t)n * DIM + d4);
    float4 s = *(const float4*)(stats + d4);
    float4 q = *(const float4*)(stats + DIM + d4);
    float4 g = *(const float4*)(gamma + d4);
    float4 bt = *(const float4*)(beta + d4);
    ushort4 o;
    {
        float mu = s.x * (1.f / NN), var = q.x * (1.f / NN) - mu * mu;
        float sc = rsqrtf(var + EPS_NORM) * g.x;
        o.x = f2bf(fmaxf(fmaf(v.x - mu, sc, bt.x), 0.f));
    }
    {
        float mu = s.y * (1.f / NN), var = q.y * (1.f / NN) - mu * mu;
        float sc = rsqrtf(var + EPS_NORM) * g.y;
        o.y = f2bf(fmaxf(fmaf(v.y - mu, sc, bt.y), 0.f));
    }
    {
        float mu = s.z * (1.f / NN), var = q.z * (1.f / NN) - mu * mu;
        float sc = rsqrtf(var + EPS_NORM) * g.z;
        o.z = f2bf(fmaxf(fmaf(v.z - mu, sc, bt.z), 0.f));
    }
    {
        float mu = s.w * (1.f / NN), var = q.w * (1.f / NN) - mu * mu;
        float sc = rsqrtf(var + EPS_NORM) * g.w;
        o.w = f2bf(fmaxf(fmaf(v.w - mu, sc, bt.w), 0.f));
    }
    *(ushort4*)(hn + (size_t)n * DIM + d4) = o;
}

// ------- GENConv softmax aggregation: wave per node, lane = 2 channels, unroll-8 -------
__global__ __launch_bounds__(256) void k_agg(const ushort* __restrict__ hn,
                                             const int4* __restrict__ erec,
                                             const int* __restrict__ row_off,
                                             const float* __restrict__ We,
                                             const float* __restrict__ be,
                                             const float* __restrict__ t_all, int l,
                                             ushort* __restrict__ ob, int N) {
    int n = blockIdx.x * 4 + (threadIdx.x >> 6);
    if (n >= N) return;
    int lane = threadIdx.x & 63;
    int d0 = lane * 2;
    float2 we = *(const float2*)(We + d0);
    float2 bd = *(const float2*)(be + d0);
    float t = t_all[l];
    int p0 = row_off[n], p1 = row_off[n + 1];
    int deg = p1 - p0;

    int mp = p0 + lane;
    int s_l = 0; float ea_l = 0.f;
    if (mp < p1) {
        int4 r = erec[mp];
        s_l = r.x; ea_l = __int_as_float(r.z);
    }

    float den0 = 0.f, num0 = 0.f, den1 = 0.f, num1 = 0.f;
    int kmax = deg < 64 ? deg : 64;
    int k = 0;
    for (; k + 8 <= kmax; k += 8) {
        int ss[8]; float ee[8]; uint hv[8];
        #pragma unroll
        for (int u = 0; u < 8; ++u) {
            ss[u] = __shfl(s_l, k + u, 64);
            ee[u] = __shfl(ea_l, k + u, 64);
        }
        #pragma unroll
        for (int u = 0; u < 8; ++u)
            hv[u] = *(const uint*)(hn + (size_t)ss[u] * DIM + d0);
        #pragma unroll
        for (int u = 0; u < 8; ++u) {
            float m0 = fmaxf(bf2f((ushort)hv[u]) + fmaf(ee[u], we.x, bd.x), 0.f) + EPS_MSG;
            float m1 = fmaxf(bf2f((ushort)(hv[u] >> 16)) + fmaf(ee[u], we.y, bd.y), 0.f) + EPS_MSG;
            float x0 = __expf(m0 * t), x1 = __expf(m1 * t);
            den0 += x0; num0 += m0 * x0; den1 += x1; num1 += m1 * x1;
        }
    }
    for (; k < kmax; ++k) {
        int s = __shfl(s_l, k, 64);
        float ea = __shfl(ea_l, k, 64);
        uint hv = *(const uint*)(hn + (size_t)s * DIM + d0);
        float m0 = fmaxf(bf2f((ushort)hv) + fmaf(ea, we.x, bd.x), 0.f) + EPS_MSG;
        float m1 = fmaxf(bf2f((ushort)(hv >> 16)) + fmaf(ea, we.y, bd.y), 0.f) + EPS_MSG;
        float x0 = __expf(m0 * t), x1 = __expf(m1 * t);
        den0 += x0; num0 += m0 * x0; den1 += x1; num1 += m1 * x1;
    }
    for (int p = p0 + 64; p < p1; ++p) {  // rare: deg > 64
        int4 r = erec[p];
        int s = r.x;
        float ea = __int_as_float(r.z);
        uint hv = *(const uint*)(hn + (size_t)s * DIM + d0);
        float m0 = fmaxf(bf2f((ushort)hv) + fmaf(ea, we.x, bd.x), 0.f) + EPS_MSG;
        float m1 = fmaxf(bf2f((ushort)(hv >> 16)) + fmaf(ea, we.y, bd.y), 0.f) + EPS_MSG;
        float x0 = __expf(m0 * t), x1 = __expf(m1 * t);
        den0 += x0; num0 += m0 * x0; den1 += x1; num1 += m1 * x1;
    }
    uint hr = *(const uint*)(hn + (size_t)n * DIM + d0);
    float a0 = (deg > 0) ? num0 / (den0 + 1e-16f) : 0.f;
    float a1 = (deg > 0) ? num1 / (den1 + 1e-16f) : 0.f;
    uint o = (uint)f2bf(a0 + bf2f((ushort)hr)) |
             ((uint)f2bf(a1 + bf2f((ushort)(hr >> 16))) << 16);
    *(uint*)(ob + (size_t)n * DIM + d0) = o;
}

// ======== fused MLP: persistent blocks, weights LDS-resident (can't remat/spill). ========
// grid=256 (1 block/CU, 148KB LDS). Per tile: 8 A-loads (double-buffered across tiles),
// LDS weight reads, 48 MFMA, LN, epilogue. W1s/W2s padded rows -> 2-way max bank alias.
template <int FIRST>
__global__ __launch_bounds__(256) void k_mlp(const ushort* __restrict__ A,
                                             const ushort* __restrict__ B1t,
                                             const float* __restrict__ b1,
                                             const float* __restrict__ g,
                                             const float* __restrict__ bv,
                                             const ushort* __restrict__ B2t,
                                             const float* __restrict__ b2,
                                             const float* __restrict__ x,
                                             const float* __restrict__ Wn,
                                             const float* __restrict__ bnb,
                                             float* __restrict__ C,
                                             ushort* __restrict__ hb,
                                             float* __restrict__ stats) {
    constexpr int LW1 = 132;  // W1s row stride (ushorts): 264B -> bank step 2
    constexpr int LW2 = 260;  // W2s row stride: 520B -> bank step 2
    constexpr int LDZ = 258;  // Zs row stride: 516B -> bank step 1
    __shared__ ushort W1s[256 * LW1];  // 67.6 KB
    __shared__ ushort W2s[128 * LW2];  // 66.6 KB
    __shared__ ushort Zs[32 * LDZ];    // 16.5 KB
    __shared__ float red_s[4][32];
    __shared__ float red_q[4][32];
    __shared__ float murs[2][32];
    const int tid = threadIdx.x;
    const int lane = tid & 63;
    const int wid = tid >> 6;
    const int wc = wid * 64;   // GEMM1 col strip
    const int wc2 = wid * 32;  // GEMM2 col strip
    const int l15 = lane & 15;
    const int lq = lane >> 4;

    // ---- stage weights into LDS (once per block; coalesced 16B copies) ----
    #pragma unroll
    for (int i = 0; i < 16; ++i) {
        int e = (tid + i * 256) * 8;       // element index in [0, 32768)
        int r = e >> 7, c = e & 127;
        *(short8v*)(W1s + r * LW1 + c) = *(const short8v*)(B1t + r * 128 + c);
    }
    #pragma unroll
    for (int i = 0; i < 16; ++i) {
        int e = (tid + i * 256) * 8;
        int r = e >> 8, c = e & 255;
        *(short8v*)(W2s + r * LW2 + c) = *(const short8v*)(B2t + r * 256 + c);
    }
    float bb[4], gg[4], lb[4];
    #pragma unroll
    for (int ni = 0; ni < 4; ++ni) {
        int col = wc + ni * 16 + l15;
        bb[ni] = b1[col]; gg[ni] = g[col]; lb[ni] = bv[col];
    }
    float b2v[2], wnc[2], bnc[2];
    #pragma unroll
    for (int ni = 0; ni < 2; ++ni) {
        int col = wc2 + ni * 16 + l15;
        b2v[ni] = b2[col];
        wnc[ni] = FIRST ? Wn[col] : 0.f;
        bnc[ni] = FIRST ? bnb[col] : 0.f;
    }
    __syncthreads();

    // ---- A double buffer: preload first tile ----
    int tile = blockIdx.x;
    short8v afr[4][2];
    if (tile < NT) {
        #pragma unroll
        for (int ks = 0; ks < 4; ++ks)
            #pragma unroll
            for (int f = 0; f < 2; ++f)
                afr[ks][f] = *(const short8v*)(A + (size_t)(tile * 32 + f * 16 + l15) * DIM +
                                               ks * 32 + lq * 8);
    }

    for (; tile < NT; tile += gridDim.x) {
        const int row0 = tile * 32;
        // ---- GEMM1: 32 x 256, K=128. B from LDS. ----
        f32x4 acc[2][4] = {};
        #pragma unroll
        for (int ks = 0; ks < 4; ++ks) {
            int kk = ks * 32 + lq * 8;
            short8v bfr[4];
            #pragma unroll
            for (int f = 0; f < 4; ++f)
                bfr[f] = *(const short8v*)(W1s + (wc + f * 16 + l15) * LW1 + kk);
            #pragma unroll
            for (int mi = 0; mi < 2; ++mi)
                #pragma unroll
                for (int ni = 0; ni < 4; ++ni)
                    acc[mi][ni] = __builtin_amdgcn_mfma_f32_16x16x32_bf16(
                        afr[ks][mi], bfr[ni], acc[mi][ni], 0, 0, 0);
        }

        // ---- prefetch next tile's A + this tile's epilogue base (hidden under LN/GEMM2) ----
        int nxt = tile + gridDim.x;
        short8v afn[4][2];
        if (nxt < NT) {
            #pragma unroll
            for (int ks = 0; ks < 4; ++ks)
                #pragma unroll
                for (int f = 0; f < 2; ++f)
                    afn[ks][f] = *(const short8v*)(A + (size_t)(nxt * 32 + f * 16 + l15) * DIM +
                                                   ks * 32 + lq * 8);
        }
        float xvv[2][4];
        float basev[2][2][4];
        if (FIRST) {
            #pragma unroll
            for (int mi = 0; mi < 2; ++mi)
                #pragma unroll
                for (int j = 0; j < 4; ++j) {
                    int gr = row0 + mi * 16 + lq * 4 + j;
                    xvv[mi][j] = (gr < NN) ? x[gr] : 0.f;
                }
        } else {
            #pragma unroll
            for (int ni = 0; ni < 2; ++ni)
                #pragma unroll
                for (int mi = 0; mi < 2; ++mi)
                    #pragma unroll
                    for (int j = 0; j < 4; ++j) {
                        int gr = row0 + mi * 16 + lq * 4 + j;
                        basev[ni][mi][j] = C[(size_t)gr * DIM + wc2 + ni * 16 + l15];
                    }
        }

        // ---- bias + LN row stats ----
        #pragma unroll
        for (int mi = 0; mi < 2; ++mi) {
            #pragma unroll
            for (int j = 0; j < 4; ++j) {
                float s = 0.f, q = 0.f;
                #pragma unroll
                for (int ni = 0; ni < 4; ++ni) {
                    float v = acc[mi][ni][j] + bb[ni];
                    acc[mi][ni][j] = v;
                    s += v; q += v * v;
                }
                #pragma unroll
                for (int off = 1; off <= 8; off <<= 1) {
                    s += __shfl_xor(s, off, 64);
                    q += __shfl_xor(q, off, 64);
                }
                if (l15 == 0) {
                    int row = mi * 16 + lq * 4 + j;
                    red_s[wid][row] = s;
                    red_q[wid][row] = q;
                }
            }
        }
        __syncthreads();
        if (tid < 32) {
            float s = red_s[0][tid] + red_s[1][tid] + red_s[2][tid] + red_s[3][tid];
            float q = red_q[0][tid] + red_q[1][tid] + red_q[2][tid] + red_q[3][tid];
            float mu = s * (1.f / HID);
            float var = q * (1.f / HID) - mu * mu;
            murs[0][tid] = mu;
            murs[1][tid] = rsqrtf(var + EPS_NORM);
        }
        __syncthreads();
        // ---- LN + ReLU -> bf16 into LDS ----
        #pragma unroll
        for (int mi = 0; mi < 2; ++mi) {
            #pragma unroll
            for (int j = 0; j < 4; ++j) {
                int row = mi * 16 + lq * 4 + j;
                float mu = murs[0][row], rs = murs[1][row];
                #pragma unroll
                for (int ni = 0; ni < 4; ++ni) {
                    float v = fmaxf(fmaf((acc[mi][ni][j] - mu) * rs, gg[ni], lb[ni]), 0.f);
                    Zs[row * LDZ + wc + ni * 16 + l15] = f2bf(v);
                }
            }
        }
        __syncthreads();

        // ---- GEMM2: 32 x 128, K=256. A from Zs, B from W2s. ----
        f32x4 acc2[2][2] = {};
        #pragma unroll
        for (int ks = 0; ks < 8; ++ks) {
            int kk = ks * 32 + lq * 8;
            short8v af2[2], bf2[2];
            #pragma unroll
            for (int f = 0; f < 2; ++f) {
                af2[f] = *(const short8v*)(Zs + (f * 16 + l15) * LDZ + kk);
                bf2[f] = *(const short8v*)(W2s + (wc2 + f * 16 + l15) * LW2 + kk);
            }
            #pragma unroll
            for (int mi = 0; mi < 2; ++mi)
                #pragma unroll
                for (int ni = 0; ni < 2; ++ni)
                    acc2[mi][ni] = __builtin_amdgcn_mfma_f32_16x16x32_bf16(
                        af2[mi], bf2[ni], acc2[mi][ni], 0, 0, 0);
        }

        // ---- epilogue ----
        float ssum[2] = {0.f, 0.f};
        float sq[2] = {0.f, 0.f};
        #pragma unroll
        for (int ni = 0; ni < 2; ++ni) {
            int col = wc2 + ni * 16 + l15;
            #pragma unroll
            for (int mi = 0; mi < 2; ++mi) {
                int rowb = row0 + mi * 16 + lq * 4;
                #pragma unroll
                for (int j = 0; j < 4; ++j) {
                    int gr = rowb + j;
                    float base = FIRST ? fmaf(xvv[mi][j], wnc[ni], bnc[ni])
                                       : basev[ni][mi][j];
                    float v = acc2[mi][ni][j] + b2v[ni] + base;
                    if (FIRST) {
                        C[(size_t)gr * DIM + col] = v;
                        bool ok = gr < NN;
                        ssum[ni] += ok ? v : 0.f;
                        sq[ni] += ok ? v * v : 0.f;
                    } else {
                        hb[(size_t)gr * DIM + col] = f2bf(v);
                    }
                }
            }
        }
        if (FIRST) {
            #pragma unroll
            for (int ni = 0; ni < 2; ++ni) {
                float s = ssum[ni], q = sq[ni];
                s += __shfl_xor(s, 16, 64); s += __shfl_xor(s, 32, 64);
                q += __shfl_xor(q, 16, 64); q += __shfl_xor(q, 32, 64);
                if (lq == 0) {
                    int col = wc2 + ni * 16 + l15;
                    atomicAdd(&stats[col], s);
                    atomicAdd(&stats[DIM + col], q);
                }
            }
        }
        // carry A double buffer
        if (nxt < NT) {
            #pragma unroll
            for (int ks = 0; ks < 4; ++ks)
                #pragma unroll
                for (int f = 0; f < 2; ++f)
                    afr[ks][f] = afn[ks][f];
        }
        __syncthreads();  // protect Zs before next tile's writes
    }
}

// ------- dot predictor, CSR order: wave per node, 4 edges/iter (16 lanes x 8 ch) -------
__global__ __launch_bounds__(256) void k_dot(const ushort* __restrict__ hb,
                                             const int4* __restrict__ erec,
                                             const int* __restrict__ row_off,
                                             float* __restrict__ out, int N) {
    int n = blockIdx.x * 4 + (threadIdx.x >> 6);
    if (n >= N) return;
    int lane = threadIdx.x & 63;
    int sub = lane >> 4;
    int l16 = lane & 15;
    float hd[8];
    {
        ushort8v hv = *(const ushort8v*)(hb + (size_t)n * DIM + l16 * 8);
        #pragma unroll
        for (int j = 0; j < 8; ++j) hd[j] = bf2f(hv[j]);
    }
    int p0 = row_off[n], p1 = row_off[n + 1];
    int deg = p1 - p0;
    int mp = p0 + lane;
    int s_l = 0, e_l = 0;
    if (mp < p1) {
        int4 r = erec[mp];
        s_l = r.x; e_l = r.y;
    }
    int kmax = deg < 64 ? deg : 64;
    for (int k = 0; k < kmax; k += 4) {
        int idx = k + sub;
        bool ok = idx < kmax;
        int s = __shfl(s_l, idx, 64);
        int e = __shfl(e_l, idx, 64);
        ushort8v av = *(const ushort8v*)(hb + (size_t)(ok ? s : n) * DIM + l16 * 8);
        float p = 0.f;
        #pragma unroll
        for (int j = 0; j < 8; ++j) p = fmaf(bf2f(av[j]), hd[j], p);
        p += __shfl_xor(p, 1, 16);
        p += __shfl_xor(p, 2, 16);
        p += __shfl_xor(p, 4, 16);
        p += __shfl_xor(p, 8, 16);
        if (ok && l16 == 0) out[e] = p;
    }
    for (int pb = p0 + 64; pb < p1; pb += 4) {  // rare: deg > 64
        int pe = pb + sub;
        bool ok = pe < p1;
        int s = n, e = 0;
        if (ok) { int4 r = erec[pe]; s = r.x; e = r.y; }
        ushort8v av = *(const ushort8v*)(hb + (size_t)s * DIM + l16 * 8);
        float p = 0.f;
        #pragma unroll
        for (int j = 0; j < 8; ++j) p = fmaf(bf2f(av[j]), hd[j], p);
        p += __shfl_xor(p, 1, 16);
        p += __shfl_xor(p, 2, 16);
        p += __shfl_xor(p, 4, 16);
        p += __shfl_xor(p, 8, 16);
        if (ok && l16 == 0) out[e] = p;
    }
}

extern "C" void kernel_launch(void* const* d_in, const int* in_sizes, int n_in,
                              void* d_out, int out_size, void* d_ws, size_t ws_size,
                              hipStream_t stream) {
    const float* x        = (const float*)d_in[0];
    const int*   ei       = (const int*)d_in[1];
    const float* eattr    = (const float*)d_in[2];
    const float* Wn       = (const float*)d_in[3];
    const float* bnb      = (const float*)d_in[4];
    const float* We       = (const float*)d_in[5];
    const float* be       = (const float*)d_in[6];
    const float* bn_gamma = (const float*)d_in[7];
    const float* bn_beta  = (const float*)d_in[8];
    const float* t_all    = (const float*)d_in[9];
    const float* W1       = (const float*)d_in[10];
    const float* b1       = (const float*)d_in[11];
    const float* ln_g     = (const float*)d_in[12];
    const float* ln_b     = (const float*)d_in[13];
    const float* W2       = (const float*)d_in[14];
    const float* b2       = (const float*)d_in[15];
    float* out = (float*)d_out;

    const int N = NN, E = NE, D = DIM, H = HID;
    const int* src = ei;
    const int* dst = ei + E;

    char* ws = (char*)d_ws;
    auto alloc = [&](size_t bytes) {
        char* p = ws;
        ws += (bytes + 255) & ~(size_t)255;
        return p;
    };
    float*  h       = (float*)alloc((size_t)MPAD * D * 4);
    ushort* ob      = (ushort*)alloc((size_t)MPAD * D * 2);
    ushort* hn      = (ushort*)alloc((size_t)MPAD * D * 2);
    ushort* hb      = (ushort*)alloc((size_t)MPAD * D * 2);
    ushort* W1t     = (ushort*)alloc((size_t)2 * D * H * 2);
    ushort* W2t     = (ushort*)alloc((size_t)2 * D * H * 2);
    int4*   erec    = (int4*)alloc((size_t)E * 16);
    int*    row_off = (int*)alloc((size_t)(N + 1) * 4);
    int*    cursor  = (int*)alloc((size_t)N * 4);
    int*    deg     = (int*)alloc((size_t)N * 4);
    int*    partials= (int*)alloc((size_t)64 * 4);
    int*    pbase   = (int*)alloc((size_t)64 * 4);
    float*  stats   = (float*)alloc((size_t)2 * D * 4);   // 1024 B
    float*  xs      = (float*)alloc((size_t)2 * 4);       // adjacent: one memset covers

    hipMemsetAsync(deg, 0, (size_t)N * 4, stream);
    hipMemsetAsync(stats, 0, 1024 + 8, stream);

    k_setup<<<64 + HIST_BLOCKS + CAST_BLOCKS, 256, 0, stream>>>(x, dst, W1, W2,
                                                                xs, deg, W1t, W2t);
    k_scanA<<<NB, 256, 0, stream>>>(deg, partials, N);
    k_scanB<<<1, 64, 0, stream>>>(partials, pbase, row_off);
    k_scanC<<<NB, 1024, 0, stream>>>(deg, pbase, row_off, cursor, N);
    k_scatter<<<(E + 255) / 256, 256, 0, stream>>>(src, dst, eattr, cursor, erec, E);
    k_hn0<<<(N * 32 + 255) / 256, 256, 0, stream>>>(x, xs, Wn, bnb, bn_gamma, bn_beta,
                                                    hn, N * 32);

    // ---- layer 0 ----
    k_agg<<<(N + 3) / 4, 256, 0, stream>>>(hn, erec, row_off, We, be, t_all, 0, ob, N);
    k_mlp<1><<<256, 256, 0, stream>>>(ob, W1t, b1, ln_g, ln_b, W2t, b2,
                                      x, Wn, bnb, h, hb, stats);
    k_bn_relu<<<(N * 32 + 255) / 256, 256, 0, stream>>>(h, stats, bn_gamma + D, bn_beta + D,
                                                        hn, N * 32);

    // ---- layer 1 ----
    k_agg<<<(N + 3) / 4, 256, 0, stream>>>(hn, erec, row_off, We, be, t_all, 1, ob, N);
    k_mlp<0><<<256, 256, 0, stream>>>(ob, W1t + (size_t)D * H, b1 + H,
                                      ln_g + H, ln_b + H, W2t + (size_t)D * H, b2 + D,
                                      x, Wn, bnb, h, hb, stats);

    k_dot<<<(N + 3) / 4, 256, 0, stream>>>(hb, erec, row_off, out, N);
}